// Round 7
// baseline (228.914 us; speedup 1.0000x reference)
//
#include <hip/hip_runtime.h>
#include <math.h>

typedef _Float16 f16;
typedef _Float16 half8 __attribute__((ext_vector_type(8)));
typedef float f32x16 __attribute__((ext_vector_type(16)));
typedef float f32x2  __attribute__((ext_vector_type(2)));

#define DEV __device__ __forceinline__

// ---------------- workspace layout (bytes) ----------------
#define W1F_OFF 0        // [L][nt2]      : 16 frags  = 16 KB
#define W2F_OFF 16384    // [L][kt4][nt2] : 64 frags  = 64 KB
#define WOF_OFF 81920    // [L][u8][kt4]  : 256 frags = 256 KB (used cols, w/h interleaved)
#define BOF_OFF 344064   // [L][u8][32] fp32 bias for used cols = 8 KB
#define SUMLOG_OFF 352256 // 1 fp32: sum over all layers/features of log|scale|

// Wout packed-column order (c in [0,32)):
//   c<16 : c even -> w_{c/2} (param c/2), c odd -> h_{c/2} (param 8+c/2)
//   16<=c<25 : d_{c-16} (param c)
//   c>=25: zero pad
#define PIDX(c) ((c) < 16 ? (((c) >> 1) + (((c) & 1) << 3)) : (c))

// ---------------- LDS layout (bytes, per block of 256 samples) -------------
#define H0_OFF    0       // [256][48]  : 16 f16/sample
#define H0_STRIDE 48
#define H_OFF     12288   // [256][144] : 64 f16/sample (128+16 pad)
#define H_STRIDE  144
#define P_OFF     49152   // [256][120] : 30 fp32/sample, 8B-aligned per thread
#define P_STRIDE  120
#define LDS_BYTES 79872

DEV float frcp(float x){ return __builtin_amdgcn_rcpf(x); }
DEV float fexp(float x){ return __expf(x); }
DEV float flog(float x){ return __logf(x); }

// tanh = 1 - 2/(e^{2x}+1). Robust without clamp.
DEV float ftanh(float x){
  float e = fexp(2.f * x);
  float r = frcp(e + 1.f);
  return fmaf(-2.f, r, 1.f);
}

// Rational-quadratic spline forward + log-det.
// p[0..15] = interleaved (w0,h0,w1,h1,...,w7,h7); p[16..24] = derivs.
// Width/height softmax+cumsum run as float2 lanes (v_pk_*_f32).
DEV void rq_spline(const float p[26], float xv, float &y_out, float &ld_out)
{
  f32x2 e[8];
  f32x2 sum = {0.f, 0.f};
#pragma unroll
  for (int k = 0; k < 8; ++k){
    f32x2 wh = {p[2*k], p[2*k+1]};
    f32x2 tt = wh * 1.44269504f;          // pk_mul: x*log2(e)
    e[k].x = exp2f(tt.x);
    e[k].y = exp2f(tt.y);
    sum += e[k];                           // pk_add
  }
  f32x2 rr; rr.x = frcp(sum.x); rr.y = frcp(sum.y);
  rr *= 19.9992f;                          // (RMAX-RMIN) - K*MIN_BIN

  f32x2 pos[9];
  pos[0].x = -10.f; pos[0].y = -10.f;
#pragma unroll
  for (int k = 0; k < 8; ++k){
    f32x2 tt = pos[k] + 1e-4f;             // pk_add
    pos[k+1] = e[k] * rr + tt;             // pk_fma  (xpos & ypos together)
  }

  int idx = 0;
#pragma unroll
  for (int j = 1; j < 8; ++j) idx += (xv >= pos[j].x) ? 1 : 0;

  f32x2 kn0 = pos[0], kn1 = pos[1];
#pragma unroll
  for (int j = 1; j < 8; ++j){
    bool sel = (idx >= j);
    kn0 = sel ? pos[j]     : kn0;
    kn1 = sel ? pos[j + 1] : kn1;
  }
  f32x2 bwh = kn1 - kn0;
  float xk = kn0.x, yk = kn0.y;
  float bw = bwh.x, bh = bwh.y;

  // derivatives: softplus only at idx and idx+1
  float uA = p[16], uB = p[17];
#pragma unroll
  for (int j = 1; j < 8; ++j){
    bool sel = (idx >= j);
    uA = sel ? p[16 + j] : uA;
    uB = sel ? p[17 + j] : uB;
  }
  float vA = uA + 0.54116666f;
  float dk  = fmaxf(vA, 0.f) + flog(1.f + fexp(-fabsf(vA))) + 1e-4f;
  float vB = uB + 0.54116666f;
  float dk1 = fmaxf(vB, 0.f) + flog(1.f + fexp(-fabsf(vB))) + 1e-4f;

  float rbw = frcp(bw);
  float s   = bh * rbw;
  float zf  = fminf(fmaxf((xv - xk) * rbw, 0.f), 1.f);
  float z1  = 1.f - zf;
  float zz  = zf * zf, z01 = zf * z1;
  float den = s + (dk1 + dk - 2.f * s) * z01;
  float rden = frcp(den);
  float yv  = yk + bh * (s * zz + dk * z01) * rden;
  float num = dk1 * zz + 2.f * s * z01 + dk * z1 * z1;
  float ldv = flog(s * s * num * rden * rden);

  bool outside = (xv <= -10.f) || (xv >= 10.f);
  y_out  = outside ? xv : yv;
  ld_out = outside ? 0.f : ldv;
}

// ---------------- prep kernel: pack fp16 B-fragments into ws ----------------
extern "C" __global__ void __launch_bounds__(256)
prep_kernel(const float* __restrict__ W1, const float* __restrict__ W2,
            const float* __restrict__ Wo, const float* __restrict__ bout,
            const float* __restrict__ scale, char* __restrict__ ws)
{
  int tid = blockIdx.x * 256 + threadIdx.x;
  if (tid < 1024){                       // W1 frags: [L][nt2]
    int fi = tid >> 6, lane = tid & 63;
    int l = fi >> 1, nt = fi & 1;
    int n = nt * 32 + (lane & 31), khi = lane >> 5;
    half8 h;
#pragma unroll
    for (int j = 0; j < 8; ++j){ int k = khi * 8 + j; h[j] = (f16)W1[l * 1024 + k * 64 + n]; }
    *(half8*)(ws + W1F_OFF + fi * 1024 + lane * 16) = h;
  } else if (tid < 5120){                // W2 frags: [L][kt4][nt2]
    int idx = tid - 1024;
    int fi = idx >> 6, lane = idx & 63;
    int l = fi >> 3, kt = (fi >> 1) & 3, nt = fi & 1;
    int n = nt * 32 + (lane & 31), khi = lane >> 5;
    half8 h;
#pragma unroll
    for (int j = 0; j < 8; ++j){ int k = kt * 16 + khi * 8 + j; h[j] = (f16)W2[l * 4096 + k * 64 + n]; }
    *(half8*)(ws + W2F_OFF + fi * 1024 + lane * 16) = h;
  } else if (tid < 21504){               // Wout used-col frags: [L][u8][kt4], w/h interleaved
    int idx = tid - 5120;
    int fi = idx >> 6, lane = idx & 63;
    int l = fi >> 5, u = (fi >> 2) & 7, kt = fi & 3;
    int f = (l & 1) + 2 * u;
    int c = lane & 31, khi = lane >> 5;
    half8 h;
#pragma unroll
    for (int j = 0; j < 8; ++j){
      int k = kt * 16 + khi * 8 + j;
      float v = (c < 25) ? Wo[l * 25600 + k * 400 + f * 25 + PIDX(c)] : 0.f;
      h[j] = (f16)v;
    }
    *(half8*)(ws + WOF_OFF + fi * 1024 + lane * 16) = h;
  } else if (tid < 23552){               // bout used cols: [L][u8][32] fp32, reordered
    int idx = tid - 21504;
    int l = idx >> 8, u = (idx >> 5) & 7, c = idx & 31;
    int f = (l & 1) + 2 * u;
    float v = (c < 25) ? bout[l * 400 + f * 25 + PIDX(c)] : 0.f;
    ((float*)(ws + BOF_OFF))[idx] = v;
  } else if (tid == 23552){              // sum of log|scale| over all layers
    float acc = 0.f;
    for (int i = 0; i < 128; ++i) acc += logf(fabsf(scale[i]));
    *(float*)(ws + SUMLOG_OFF) = acc;
  }
}

// Produce feature params: MFMA into C-layout, masked store to P slot, then
// immediately issue this thread's own-sample reads (b64). In-order per-wave
// DS semantics make read-after-store correct; the consumer spline (which runs
// later) covers the LDS latency.
DEV void produce_p(const half8 bf[4], float bias, const half8 a2[2][4],
                   char* lds, const char* pbase,
                   int ln31, int wv, int rowbase, float* pout)
{
  f32x16 dp0, dp1;
#pragma unroll
  for (int i = 0; i < 16; ++i){ dp0[i] = bias; dp1[i] = bias; }
#pragma unroll
  for (int kt = 0; kt < 4; ++kt){
    dp0 = __builtin_amdgcn_mfma_f32_32x32x16_f16(a2[0][kt], bf[kt], dp0, 0, 0, 0);
    dp1 = __builtin_amdgcn_mfma_f32_32x32x16_f16(a2[1][kt], bf[kt], dp1, 0, 0, 0);
  }
  if (ln31 < 25){
#pragma unroll
    for (int i = 0; i < 16; ++i){
      int row = (i & 3) + 8 * (i >> 2) + rowbase;
      int s0 = wv * 64 + row;
      *(float*)(lds + P_OFF + s0 * P_STRIDE + ln31 * 4) = dp0[i];
      *(float*)(lds + P_OFF + (s0 + 32) * P_STRIDE + ln31 * 4) = dp1[i];
    }
  }
#pragma unroll
  for (int j = 0; j < 13; ++j){
    f32x2 v = *(const f32x2*)(pbase + 8 * j);
    pout[2*j] = v.x; pout[2*j+1] = v.y;
  }
}

// ---------------- one coupling layer (all LDS traffic wave-private) --------
template<int PAR>
DEV void layer_mfma(int l,
                    const float* __restrict__ W0, const float* __restrict__ b0,
                    const float* __restrict__ b1v, const float* __restrict__ b2v,
                    const float* __restrict__ scv, const float* __restrict__ shv,
                    const char* __restrict__ ws, char* lds,
                    float (&z)[16], float &logdet,
                    int t, int lane, int wv, int ln31, int khi)
{
  const float* w0  = W0 + l * 256;
  const float* bb0 = b0 + l * 16;
  const int rowbase = khi * 4;     // C/D layout: row = (i&3)+8*(i>>2)+4*(lane>>5)
  const char* pbase = lds + P_OFF + t * P_STRIDE;

  // ---- hoisted weight-fragment loads (latency hidden behind h0 VALU) ----
  const half8* W1F = (const half8*)(ws + W1F_OFF);
  const half8* W2F = (const half8*)(ws + W2F_OFF);
  half8 w1f[2];
#pragma unroll
  for (int nt = 0; nt < 2; ++nt) w1f[nt] = W1F[(l * 2 + nt) * 64 + lane];
  half8 w2f[8];
#pragma unroll
  for (int kt = 0; kt < 4; ++kt)
#pragma unroll
    for (int nt = 0; nt < 2; ++nt)
      w2f[kt * 2 + nt] = W2F[((l * 4 + kt) * 2 + nt) * 64 + lane];
  float bias1[2], bias2[2];
#pragma unroll
  for (int nt = 0; nt < 2; ++nt){
    bias1[nt] = b1v[l * 64 + nt * 32 + ln31];
    bias2[nt] = b2v[l * 64 + nt * 32 + ln31];
  }

  // ---- h0 = tanh(mz @ W0 + b0), per-thread VALU ----
  float h0[16];
#pragma unroll
  for (int j = 0; j < 16; ++j) h0[j] = bb0[j];
#pragma unroll
  for (int u = 0; u < 8; ++u){
    const int f = (1 - PAR) + 2 * u;
    const float v = z[f];
#pragma unroll
    for (int j = 0; j < 16; ++j) h0[j] = fmaf(v, w0[f * 16 + j], h0[j]);
  }
  {
    half8 lo, hi;
#pragma unroll
    for (int j = 0; j < 8; ++j){ lo[j] = (f16)ftanh(h0[j]); hi[j] = (f16)ftanh(h0[8 + j]); }
    *(half8*)(lds + H0_OFF + t * H0_STRIDE)      = lo;
    *(half8*)(lds + H0_OFF + t * H0_STRIDE + 16) = hi;
  }

  // ---- W1: h1 = tanh(h0 @ W1 + b1) via MFMA (bias folded into acc init) ----
  half8 a0[2];
#pragma unroll
  for (int mt = 0; mt < 2; ++mt){
    int s = wv * 64 + mt * 32 + ln31;
    a0[mt] = *(const half8*)(lds + H0_OFF + s * H0_STRIDE + khi * 16);
  }
  f32x16 d1[2][2];
#pragma unroll
  for (int mt = 0; mt < 2; ++mt)
#pragma unroll
    for (int nt = 0; nt < 2; ++nt)
#pragma unroll
      for (int i = 0; i < 16; ++i) d1[mt][nt][i] = bias1[nt];
#pragma unroll
  for (int nt = 0; nt < 2; ++nt)
#pragma unroll
    for (int mt = 0; mt < 2; ++mt)
      d1[mt][nt] = __builtin_amdgcn_mfma_f32_32x32x16_f16(a0[mt], w1f[nt], d1[mt][nt], 0, 0, 0);
#pragma unroll
  for (int mt = 0; mt < 2; ++mt)
#pragma unroll
    for (int nt = 0; nt < 2; ++nt)
#pragma unroll
      for (int i = 0; i < 16; ++i){
        int row = (i & 3) + 8 * (i >> 2) + rowbase;
        int s = wv * 64 + mt * 32 + row;
        float v = ftanh(d1[mt][nt][i]);
        *(f16*)(lds + H_OFF + s * H_STRIDE + (nt * 32 + ln31) * 2) = (f16)v;
      }

  // ---- W2: h2 = h1 @ W2 + b2 via MFMA (bias folded) ----
  half8 a1[2][4];
#pragma unroll
  for (int mt = 0; mt < 2; ++mt){
    int s = wv * 64 + mt * 32 + ln31;
#pragma unroll
    for (int kt = 0; kt < 4; ++kt)
      a1[mt][kt] = *(const half8*)(lds + H_OFF + s * H_STRIDE + kt * 32 + khi * 16);
  }
  f32x16 d2[2][2];
#pragma unroll
  for (int mt = 0; mt < 2; ++mt)
#pragma unroll
    for (int nt = 0; nt < 2; ++nt)
#pragma unroll
      for (int i = 0; i < 16; ++i) d2[mt][nt][i] = bias2[nt];
#pragma unroll
  for (int kt = 0; kt < 4; ++kt)
#pragma unroll
    for (int nt = 0; nt < 2; ++nt)
#pragma unroll
      for (int mt = 0; mt < 2; ++mt)
        d2[mt][nt] = __builtin_amdgcn_mfma_f32_32x32x16_f16(a1[mt][kt], w2f[kt * 2 + nt], d2[mt][nt], 0, 0, 0);

  // ---- prefetch production 0's Wout frags (hidden behind W2 epilogue) ----
  const half8* WOF = (const half8*)(ws + WOF_OFF);
  const float* BOF = (const float*)(ws + BOF_OFF);
  half8 bfa[4], bfb[4];
  float ba, bb;
#pragma unroll
  for (int kt = 0; kt < 4; ++kt) bfa[kt] = WOF[((l * 8 + 0) * 4 + kt) * 64 + lane];
  ba = BOF[(l * 8 + 0) * 32 + ln31];

#pragma unroll
  for (int mt = 0; mt < 2; ++mt)
#pragma unroll
    for (int nt = 0; nt < 2; ++nt)
#pragma unroll
      for (int i = 0; i < 16; ++i){
        int row = (i & 3) + 8 * (i >> 2) + rowbase;
        int s = wv * 64 + mt * 32 + row;
        *(f16*)(lds + H_OFF + s * H_STRIDE + (nt * 32 + ln31) * 2) = (f16)d2[mt][nt][i];
      }

  // ---- h2 A-fragments (reused across all 8 features) ----
  half8 a2[2][4];
#pragma unroll
  for (int mt = 0; mt < 2; ++mt){
    int s = wv * 64 + mt * 32 + ln31;
#pragma unroll
    for (int kt = 0; kt < 4; ++kt)
      a2[mt][kt] = *(const half8*)(lds + H_OFF + s * H_STRIDE + kt * 32 + khi * 16);
  }

  // ---- feature pipeline: production k+1 issued (MFMA + store + own-read)
  //      before spline(k); p double-buffered in registers, single LDS slot.
  float pA[26], pB[26];
  produce_p(bfa, ba, a2, lds, pbase, ln31, wv, rowbase, pA);   // production 0
#pragma unroll
  for (int kt = 0; kt < 4; ++kt) bfb[kt] = WOF[((l * 8 + 1) * 4 + kt) * 64 + lane];
  bb = BOF[(l * 8 + 1) * 32 + ln31];

#pragma unroll 1
  for (int u = 0; u < 8; u += 2){
    // production u+1 (always: u <= 6)
    produce_p(bfb, bb, a2, lds, pbase, ln31, wv, rowbase, pB);
    if (u < 6){
#pragma unroll
      for (int kt = 0; kt < 4; ++kt) bfa[kt] = WOF[((l * 8 + u + 2) * 4 + kt) * 64 + lane];
      ba = BOF[(l * 8 + u + 2) * 32 + ln31];
    }
    {
      float y, ld;
      rq_spline(pA, z[PAR + 2 * u], y, ld);
      z[PAR + 2 * u] = y;
      logdet += ld;
    }
    if (u < 6){
      produce_p(bfa, ba, a2, lds, pbase, ln31, wv, rowbase, pA); // production u+2
#pragma unroll
      for (int kt = 0; kt < 4; ++kt) bfb[kt] = WOF[((l * 8 + u + 3) * 4 + kt) * 64 + lane];
      bb = BOF[(l * 8 + u + 3) * 32 + ln31];
    }
    {
      float y, ld;
      rq_spline(pB, z[PAR + 2 * u + 2 - 1 + 1], y, ld);  // feature u+1
      z[PAR + 2 * (u + 1)] = y;
      logdet += ld;
    }
  }

  // ---- affine (log|scale| sum precomputed in prep) ----
  const float* scp = scv + l * 16;
  const float* shp = shv + l * 16;
#pragma unroll
  for (int j = 0; j < 16; ++j)
    z[j] = fmaf(z[j], scp[j], shp[j]);
}

extern "C" __global__ void __launch_bounds__(256, 2)
flow_kernel(const float* __restrict__ x,
            const float* __restrict__ W0, const float* __restrict__ b0,
            const float* __restrict__ b1v, const float* __restrict__ b2v,
            const float* __restrict__ scv, const float* __restrict__ shv,
            const char* __restrict__ ws, float* __restrict__ out, int B)
{
  extern __shared__ char lds[];
  const int t    = threadIdx.x;
  const int lane = t & 63;
  const int wv   = t >> 6;
  const int ln31 = lane & 31;
  const int khi  = lane >> 5;
  const int g    = blockIdx.x * 256 + t;

  float z[16];
  const float4* xv = reinterpret_cast<const float4*>(x + (size_t)g * 16);
  float4 a0 = xv[0], a1 = xv[1], a2 = xv[2], a3 = xv[3];
  z[0]=a0.x; z[1]=a0.y; z[2]=a0.z; z[3]=a0.w;
  z[4]=a1.x; z[5]=a1.y; z[6]=a1.z; z[7]=a1.w;
  z[8]=a2.x; z[9]=a2.y; z[10]=a2.z; z[11]=a2.w;
  z[12]=a3.x; z[13]=a3.y; z[14]=a3.z; z[15]=a3.w;

  float logdet = 0.f;
  for (int l = 7; l >= 0; --l){
    if (l & 1) layer_mfma<1>(l, W0, b0, b1v, b2v, scv, shv, ws, lds, z, logdet, t, lane, wv, ln31, khi);
    else       layer_mfma<0>(l, W0, b0, b1v, b2v, scv, shv, ws, lds, z, logdet, t, lane, wv, ln31, khi);
  }

  float sumlog = *(const float*)(ws + SUMLOG_OFF);
  float ss = 0.f;
#pragma unroll
  for (int j = 0; j < 16; ++j) ss = fmaf(z[j], z[j], ss);
  out[g] = -0.5f * ss - 14.7030165f + logdet + sumlog;
}

extern "C" void kernel_launch(void* const* d_in, const int* in_sizes, int n_in,
                              void* d_out, int out_size, void* d_ws, size_t ws_size,
                              hipStream_t stream)
{
  const float* x    = (const float*)d_in[0];
  const float* W0   = (const float*)d_in[1];
  const float* b0   = (const float*)d_in[2];
  const float* W1   = (const float*)d_in[3];
  const float* b1   = (const float*)d_in[4];
  const float* W2   = (const float*)d_in[5];
  const float* b2   = (const float*)d_in[6];
  const float* Wout = (const float*)d_in[7];
  const float* bout = (const float*)d_in[8];
  const float* scale= (const float*)d_in[9];
  const float* shift= (const float*)d_in[10];

  int B = in_sizes[0] / 16;

  hipLaunchKernelGGL(prep_kernel, dim3(93), dim3(256), 0, stream,
                     W1, W2, Wout, bout, scale, (char*)d_ws);

  hipLaunchKernelGGL(flow_kernel, dim3(B / 256), dim3(256), LDS_BYTES, stream,
                     x, W0, b0, b1, b2, scale, shift,
                     (const char*)d_ws, (float*)d_out, B);
}

// Round 8
// 216.425 us; speedup vs baseline: 1.0577x; 1.0577x over previous
//
#include <hip/hip_runtime.h>
#include <math.h>

typedef _Float16 f16;
typedef _Float16 half8 __attribute__((ext_vector_type(8)));
typedef float f32x16 __attribute__((ext_vector_type(16)));

#define DEV __device__ __forceinline__

// ---------------- workspace layout (bytes) ----------------
#define W1F_OFF 0        // [L][nt2]      : 16 frags  = 16 KB
#define W2F_OFF 16384    // [L][kt4][nt2] : 64 frags  = 64 KB
#define WOF_OFF 81920    // [L][u8][kt4]  : 256 frags = 256 KB (used cols, 32-padded)
#define BOF_OFF 344064   // [L][u8][32] fp32 bias for used cols = 8 KB
#define SUMLOG_OFF 352256 // 1 fp32: sum over all layers/features of log|scale|

// ---------------- LDS layout ----------------
// Per-wave private 6400 B chunk at lds + wv*6400. Within a chunk, regions
// alias in time (all DS ops are same-wave, in-order):
//   H phase: 32 samples x 144 B (h1 then h2, f16, 128+16 pad)      = 4608 B
//   P phase: 2 slots x 32 samples x 100 B (25 fp32 spline params)  = 6400 B
#define WCHUNK    6400
#define H_STRIDE  144
#define P_SLOT    3200
#define P_STRIDE  100
#define LDS_BYTES 25600   // 4 waves * 6400

DEV float frcp(float x){ return __builtin_amdgcn_rcpf(x); }
DEV float fexp(float x){ return __expf(x); }
DEV float flog(float x){ return __logf(x); }

// tanh = 1 - 2/(e^{2x}+1). Robust without clamp (saturates correctly at +-inf).
DEV float ftanh(float x){
  float e = fexp(2.f * x);
  float r = frcp(e + 1.f);
  return fmaf(-2.f, r, 1.f);
}

// Rational-quadratic spline forward + log-det (fp32, per-thread).
// p[0:8]=unnorm widths, p[8:16]=unnorm heights, p[16:25]=unnorm derivs.
// No softmax max-sub (|p| small), only 2 softplus (idx, idx+1),
// masked partial sum for y-knot.
DEV void rq_spline(const float p[25], float xv, float &y_out, float &ld_out)
{
  float ew[8]; float sw = 0.f;
#pragma unroll
  for (int k = 0; k < 8; ++k){ ew[k] = fexp(p[k]); sw += ew[k]; }
  float rw = frcp(sw) * 19.9992f;           // (RMAX-RMIN) - K*MIN_BIN

  float xpos[9];
  xpos[0] = -10.f;
#pragma unroll
  for (int k = 0; k < 8; ++k) xpos[k + 1] = xpos[k] + fmaf(ew[k], rw, 1e-4f);

  int idx = 0;
#pragma unroll
  for (int j = 1; j < 8; ++j) idx += (xv >= xpos[j]) ? 1 : 0;

  float xk = xpos[0], ewk = ew[0];
#pragma unroll
  for (int j = 1; j < 8; ++j){
    bool sel = (idx >= j);
    xk  = sel ? xpos[j] : xk;
    ewk = sel ? ew[j]   : ewk;
  }
  float bw = fmaf(ewk, rw, 1e-4f);

  float eh[8]; float shs = 0.f;
#pragma unroll
  for (int k = 0; k < 8; ++k){ eh[k] = fexp(p[8 + k]); shs += eh[k]; }
  float rh = frcp(shs) * 19.9992f;

  float S = 0.f, ehk = eh[0];
#pragma unroll
  for (int k = 1; k < 8; ++k){
    bool sel = (idx >= k);
    S   += sel ? eh[k - 1] : 0.f;
    ehk  = sel ? eh[k]     : ehk;
  }
  float yk = fmaf(S, rh, fmaf((float)idx, 1e-4f, -10.f));
  float bh = fmaf(ehk, rh, 1e-4f);

  float uA = p[16], uB = p[17];
#pragma unroll
  for (int j = 1; j < 8; ++j){
    bool sel = (idx >= j);
    uA = sel ? p[16 + j] : uA;
    uB = sel ? p[17 + j] : uB;
  }
  float vA = uA + 0.54116666f;
  float dk  = fmaxf(vA, 0.f) + flog(1.f + fexp(-fabsf(vA))) + 1e-4f;
  float vB = uB + 0.54116666f;
  float dk1 = fmaxf(vB, 0.f) + flog(1.f + fexp(-fabsf(vB))) + 1e-4f;

  float rbw = frcp(bw);
  float s   = bh * rbw;
  float zf  = fminf(fmaxf((xv - xk) * rbw, 0.f), 1.f);
  float z1  = 1.f - zf;
  float zz  = zf * zf, z01 = zf * z1;
  float den = s + (dk1 + dk - 2.f * s) * z01;
  float rden = frcp(den);
  float yv  = yk + bh * (s * zz + dk * z01) * rden;
  float num = dk1 * zz + 2.f * s * z01 + dk * z1 * z1;
  float ldv = flog(s * s * num * rden * rden);

  bool outside = (xv <= -10.f) || (xv >= 10.f);
  y_out  = outside ? xv : yv;
  ld_out = outside ? 0.f : ldv;
}

// ---------------- prep kernel: pack fp16 B-fragments into ws ----------------
extern "C" __global__ void __launch_bounds__(256)
prep_kernel(const float* __restrict__ W1, const float* __restrict__ W2,
            const float* __restrict__ Wo, const float* __restrict__ bout,
            const float* __restrict__ scale, char* __restrict__ ws)
{
  int tid = blockIdx.x * 256 + threadIdx.x;
  if (tid < 1024){                       // W1 frags: [L][nt2]
    int fi = tid >> 6, lane = tid & 63;
    int l = fi >> 1, nt = fi & 1;
    int n = nt * 32 + (lane & 31), khi = lane >> 5;
    half8 h;
#pragma unroll
    for (int j = 0; j < 8; ++j){ int k = khi * 8 + j; h[j] = (f16)W1[l * 1024 + k * 64 + n]; }
    *(half8*)(ws + W1F_OFF + fi * 1024 + lane * 16) = h;
  } else if (tid < 5120){                // W2 frags: [L][kt4][nt2]
    int idx = tid - 1024;
    int fi = idx >> 6, lane = idx & 63;
    int l = fi >> 3, kt = (fi >> 1) & 3, nt = fi & 1;
    int n = nt * 32 + (lane & 31), khi = lane >> 5;
    half8 h;
#pragma unroll
    for (int j = 0; j < 8; ++j){ int k = kt * 16 + khi * 8 + j; h[j] = (f16)W2[l * 4096 + k * 64 + n]; }
    *(half8*)(ws + W2F_OFF + fi * 1024 + lane * 16) = h;
  } else if (tid < 21504){               // Wout used-col frags: [L][u8][kt4]
    int idx = tid - 5120;
    int fi = idx >> 6, lane = idx & 63;
    int l = fi >> 5, u = (fi >> 2) & 7, kt = fi & 3;
    int f = (l & 1) + 2 * u;
    int c = lane & 31, khi = lane >> 5;
    half8 h;
#pragma unroll
    for (int j = 0; j < 8; ++j){
      int k = kt * 16 + khi * 8 + j;
      float v = (c < 25) ? Wo[l * 25600 + k * 400 + f * 25 + c] : 0.f;
      h[j] = (f16)v;
    }
    *(half8*)(ws + WOF_OFF + fi * 1024 + lane * 16) = h;
  } else if (tid < 23552){               // bout used cols: [L][u8][32] fp32
    int idx = tid - 21504;
    int l = idx >> 8, u = (idx >> 5) & 7, c = idx & 31;
    int f = (l & 1) + 2 * u;
    float v = (c < 25) ? bout[l * 400 + f * 25 + c] : 0.f;
    ((float*)(ws + BOF_OFF))[idx] = v;
  } else if (tid == 23552){              // sum of log|scale| over all layers
    float acc = 0.f;
    for (int i = 0; i < 128; ++i) acc += logf(fabsf(scale[i]));
    *(float*)(ws + SUMLOG_OFF) = acc;
  }
}

// ---------------- one coupling layer ----------------
// Wave owns 32 samples; lane pair (ln31, khi=0/1) shares sample sid.
// khi=0 splines features PAR+2it (it=0..3), khi=1 splines PAR+2it+8 —
// concurrently, no divergence. z exchanged via shfl_xor(32) at layer end.
template<int PAR>
DEV void layer_mfma(int l,
                    const float* __restrict__ W0, const float* __restrict__ b0,
                    const float* __restrict__ b1v, const float* __restrict__ b2v,
                    const float* __restrict__ scv, const float* __restrict__ shv,
                    const char* __restrict__ ws, char* wlds /*per-wave chunk*/,
                    float (&z)[16], float &logdet,
                    int lane, int ln31, int khi)
{
  const float* w0  = W0 + l * 256;
  const float* bb0 = b0 + l * 16;
  const int rowbase = khi * 4;     // C/D layout: row = (i&3)+8*(i>>2)+4*khi

  // ---- hoisted W1 fragment + bias loads (latency hidden behind h0) ----
  const half8* W1F = (const half8*)(ws + W1F_OFF);
  const half8* W2F = (const half8*)(ws + W2F_OFF);
  half8 w1f[2];
#pragma unroll
  for (int nt = 0; nt < 2; ++nt) w1f[nt] = W1F[(l * 2 + nt) * 64 + lane];
  float bias1[2], bias2[2];
#pragma unroll
  for (int nt = 0; nt < 2; ++nt){
    bias1[nt] = b1v[l * 64 + nt * 32 + ln31];
    bias2[nt] = b2v[l * 64 + nt * 32 + ln31];
  }

  // ---- h0 = tanh(mz @ W0 + b0): full 16 outputs per thread (scalar w0),
  //      then each thread keeps its khi-half as its W1 A-fragment. No LDS. ----
  float h0[16];
#pragma unroll
  for (int j = 0; j < 16; ++j) h0[j] = bb0[j];
#pragma unroll
  for (int u = 0; u < 8; ++u){
    const int f = (1 - PAR) + 2 * u;
    const float v = z[f];
#pragma unroll
    for (int j = 0; j < 16; ++j) h0[j] = fmaf(v, w0[f * 16 + j], h0[j]);
  }
  half8 a0;
#pragma unroll
  for (int j = 0; j < 8; ++j){
    float hv = khi ? h0[j + 8] : h0[j];
    a0[j] = (f16)ftanh(hv);
  }

  // ---- W1: h1 = tanh(h0 @ W1 + b1), 1 m-tile ----
  f32x16 d1[2];
#pragma unroll
  for (int nt = 0; nt < 2; ++nt)
#pragma unroll
    for (int i = 0; i < 16; ++i) d1[nt][i] = bias1[nt];
#pragma unroll
  for (int nt = 0; nt < 2; ++nt)
    d1[nt] = __builtin_amdgcn_mfma_f32_32x32x16_f16(a0, w1f[nt], d1[nt], 0, 0, 0);

  // load W2 frags now; epilogue below covers the latency
  half8 w2f[8];
#pragma unroll
  for (int kt = 0; kt < 4; ++kt)
#pragma unroll
    for (int nt = 0; nt < 2; ++nt)
      w2f[kt * 2 + nt] = W2F[((l * 4 + kt) * 2 + nt) * 64 + lane];

#pragma unroll
  for (int nt = 0; nt < 2; ++nt)
#pragma unroll
    for (int i = 0; i < 16; ++i){
      int row = (i & 3) + 8 * (i >> 2) + rowbase;
      *(f16*)(wlds + row * H_STRIDE + (nt * 32 + ln31) * 2) = (f16)ftanh(d1[nt][i]);
    }

  // ---- W2: h2 = h1 @ W2 + b2 ----
  half8 a1[4];
#pragma unroll
  for (int kt = 0; kt < 4; ++kt)
    a1[kt] = *(const half8*)(wlds + ln31 * H_STRIDE + kt * 32 + khi * 16);
  f32x16 d2[2];
#pragma unroll
  for (int nt = 0; nt < 2; ++nt)
#pragma unroll
    for (int i = 0; i < 16; ++i) d2[nt][i] = bias2[nt];
#pragma unroll
  for (int kt = 0; kt < 4; ++kt)
#pragma unroll
    for (int nt = 0; nt < 2; ++nt)
      d2[nt] = __builtin_amdgcn_mfma_f32_32x32x16_f16(a1[kt], w2f[kt * 2 + nt], d2[nt], 0, 0, 0);
#pragma unroll
  for (int nt = 0; nt < 2; ++nt)
#pragma unroll
    for (int i = 0; i < 16; ++i){
      int row = (i & 3) + 8 * (i >> 2) + rowbase;
      *(f16*)(wlds + row * H_STRIDE + (nt * 32 + ln31) * 2) = (f16)d2[nt][i];
    }

  // ---- h2 A-fragments (reused across all 4 production iterations) ----
  half8 a2[4];
#pragma unroll
  for (int kt = 0; kt < 4; ++kt)
    a2[kt] = *(const half8*)(wlds + ln31 * H_STRIDE + kt * 32 + khi * 16);

  // ---- paired productions + splines ----
  const half8* WOF = (const half8*)(ws + WOF_OFF);
  const float* BOF = (const float*)(ws + BOF_OFF);
#pragma unroll 1
  for (int it = 0; it < 4; ++it){
    half8 bfA[4], bfB[4];
#pragma unroll
    for (int kt = 0; kt < 4; ++kt){
      bfA[kt] = WOF[((l * 8 + it) * 4 + kt) * 64 + lane];
      bfB[kt] = WOF[((l * 8 + it + 4) * 4 + kt) * 64 + lane];
    }
    float biasA = BOF[(l * 8 + it) * 32 + ln31];
    float biasB = BOF[(l * 8 + it + 4) * 32 + ln31];

    f32x16 dpA, dpB;
#pragma unroll
    for (int i = 0; i < 16; ++i){ dpA[i] = biasA; dpB[i] = biasB; }
#pragma unroll
    for (int kt = 0; kt < 4; ++kt){
      dpA = __builtin_amdgcn_mfma_f32_32x32x16_f16(a2[kt], bfA[kt], dpA, 0, 0, 0);
      dpB = __builtin_amdgcn_mfma_f32_32x32x16_f16(a2[kt], bfB[kt], dpB, 0, 0, 0);
    }
    if (ln31 < 25){
#pragma unroll
      for (int i = 0; i < 16; ++i){
        int row = (i & 3) + 8 * (i >> 2) + rowbase;
        *(float*)(wlds + row * P_STRIDE + ln31 * 4)          = dpA[i];
        *(float*)(wlds + P_SLOT + row * P_STRIDE + ln31 * 4) = dpB[i];
      }
    }
    // own-sample read from own khi-slot (in-order per-wave DS => safe)
    const char* pb = wlds + khi * P_SLOT + ln31 * P_STRIDE;
    float p[25];
#pragma unroll
    for (int j = 0; j < 25; ++j) p[j] = *(const float*)(pb + j * 4);

    float xlo = z[PAR + 2 * it], xhi = z[PAR + 2 * it + 8];
    float xin = khi ? xhi : xlo;
    float y, ld;
    rq_spline(p, xin, y, ld);
    logdet += ld;
    z[PAR + 2 * it]     = khi ? xlo : y;
    z[PAR + 2 * it + 8] = khi ? y : xhi;
  }

  // ---- exchange transformed features between the khi-halves ----
#pragma unroll
  for (int it = 0; it < 4; ++it){
    float mine  = khi ? z[PAR + 2 * it + 8] : z[PAR + 2 * it];
    float other = __shfl_xor(mine, 32, 64);
    z[PAR + 2 * it]     = khi ? other : z[PAR + 2 * it];
    z[PAR + 2 * it + 8] = khi ? z[PAR + 2 * it + 8] : other;
  }

  // ---- affine (log|scale| sum precomputed in prep) ----
  const float* scp = scv + l * 16;
  const float* shp = shv + l * 16;
#pragma unroll
  for (int j = 0; j < 16; ++j)
    z[j] = fmaf(z[j], scp[j], shp[j]);
}

extern "C" __global__ void __launch_bounds__(256, 4)
flow_kernel(const float* __restrict__ x,
            const float* __restrict__ W0, const float* __restrict__ b0,
            const float* __restrict__ b1v, const float* __restrict__ b2v,
            const float* __restrict__ scv, const float* __restrict__ shv,
            const char* __restrict__ ws, float* __restrict__ out, int B)
{
  extern __shared__ char lds[];
  const int t    = threadIdx.x;
  const int lane = t & 63;
  const int wv   = t >> 6;
  const int ln31 = lane & 31;
  const int khi  = lane >> 5;
  char* wlds = lds + wv * WCHUNK;          // per-wave private chunk

  const int sid = wv * 32 + ln31;          // sample within block (0..127)
  const int g   = blockIdx.x * 128 + sid;  // global sample

  float z[16];
  const float4* xv = reinterpret_cast<const float4*>(x + (size_t)g * 16);
  float4 a0 = xv[0], a1 = xv[1], a2 = xv[2], a3 = xv[3];
  z[0]=a0.x; z[1]=a0.y; z[2]=a0.z; z[3]=a0.w;
  z[4]=a1.x; z[5]=a1.y; z[6]=a1.z; z[7]=a1.w;
  z[8]=a2.x; z[9]=a2.y; z[10]=a2.z; z[11]=a2.w;
  z[12]=a3.x; z[13]=a3.y; z[14]=a3.z; z[15]=a3.w;

  float logdet = 0.f;
  for (int l = 7; l >= 0; --l){
    if (l & 1) layer_mfma<1>(l, W0, b0, b1v, b2v, scv, shv, ws, wlds, z, logdet, lane, ln31, khi);
    else       layer_mfma<0>(l, W0, b0, b1v, b2v, scv, shv, ws, wlds, z, logdet, lane, ln31, khi);
  }

  // combine the pair's logdet halves
  float ldtot = logdet + __shfl_xor(logdet, 32, 64);

  float sumlog = *(const float*)(ws + SUMLOG_OFF);
  float ss = 0.f;
#pragma unroll
  for (int j = 0; j < 16; ++j) ss = fmaf(z[j], z[j], ss);
  if (khi == 0)
    out[g] = -0.5f * ss - 14.7030165f + ldtot + sumlog;
}

extern "C" void kernel_launch(void* const* d_in, const int* in_sizes, int n_in,
                              void* d_out, int out_size, void* d_ws, size_t ws_size,
                              hipStream_t stream)
{
  const float* x    = (const float*)d_in[0];
  const float* W0   = (const float*)d_in[1];
  const float* b0   = (const float*)d_in[2];
  const float* W1   = (const float*)d_in[3];
  const float* b1   = (const float*)d_in[4];
  const float* W2   = (const float*)d_in[5];
  const float* b2   = (const float*)d_in[6];
  const float* Wout = (const float*)d_in[7];
  const float* bout = (const float*)d_in[8];
  const float* scale= (const float*)d_in[9];
  const float* shift= (const float*)d_in[10];

  int B = in_sizes[0] / 16;

  hipLaunchKernelGGL(prep_kernel, dim3(93), dim3(256), 0, stream,
                     W1, W2, Wout, bout, scale, (char*)d_ws);

  hipLaunchKernelGGL(flow_kernel, dim3(B / 128), dim3(256), LDS_BYTES, stream,
                     x, W0, b0, b1, b2, scale, shift,
                     (const char*)d_ws, (float*)d_out, B);
}

// Round 9
// 213.319 us; speedup vs baseline: 1.0731x; 1.0146x over previous
//
#include <hip/hip_runtime.h>
#include <math.h>

typedef _Float16 f16;
typedef _Float16 half8 __attribute__((ext_vector_type(8)));
typedef float f32x16 __attribute__((ext_vector_type(16)));

#define DEV __device__ __forceinline__

// ---------------- workspace layout (bytes) ----------------
#define W1F_OFF 0        // [L][nt2]      : 16 frags  = 16 KB
#define W2F_OFF 16384    // [L][kt4][nt2] : 64 frags  = 64 KB
#define WOF_OFF 81920    // [L][u8][kt4]  : 256 frags = 256 KB (used cols, 32-padded)
#define BOF_OFF 344064   // [L][u8][32] fp32 bias for used cols = 8 KB
#define SUMLOG_OFF 352256 // 1 fp32: sum over all layers/features of log|scale|

// ---------------- LDS layout ----------------
// Per-wave private 6400 B chunk at lds + wv*6400. Regions alias in time
// (all DS ops are same-wave, in-order):
//   H phase: 32 samples x 144 B (h1 then h2, f16, 128+16 pad)      = 4608 B
//   P phase: 2 slots x 32 samples x 100 B (25 fp32 spline params)  = 6400 B
#define WCHUNK    6400
#define H_STRIDE  144
#define P_SLOT    3200
#define P_STRIDE  100
#define LDS_BYTES 25600   // 4 waves * 6400

DEV float frcp(float x){ return __builtin_amdgcn_rcpf(x); }
DEV float fexp(float x){ return __expf(x); }
DEV float flog(float x){ return __logf(x); }

// tanh = 1 - 2/(e^{2x}+1). Robust without clamp (saturates correctly at +-inf).
DEV float ftanh(float x){
  float e = fexp(2.f * x);
  float r = frcp(e + 1.f);
  return fmaf(-2.f, r, 1.f);
}

// Rational-quadratic spline forward + log-det (fp32, per-thread).
// p[0:8]=unnorm widths, p[8:16]=unnorm heights, p[16:25]=unnorm derivs.
// Register-lean: running-cumsum x-path (no xpos array), masked partial sum
// for the y-knot, softplus only at idx and idx+1.
DEV void rq_spline(const float p[25], float xv, float &y_out, float &ld_out)
{
  float ew[8]; float sw = 0.f;
#pragma unroll
  for (int k = 0; k < 8; ++k){ ew[k] = fexp(p[k]); sw += ew[k]; }
  float rw = frcp(sw) * 19.9992f;           // (RMAX-RMIN) - K*MIN_BIN

  // x-path: running cumulative knot; select bin containing xv
  int idx = 0;
  float xk = -10.f, ewk = ew[0];
  float cum = fmaf(ew[0], rw, -10.f + 1e-4f);   // xpos[1]
#pragma unroll
  for (int j = 1; j < 8; ++j){
    bool sel = (xv >= cum);
    idx += sel ? 1 : 0;
    xk  = sel ? cum   : xk;
    ewk = sel ? ew[j] : ewk;
    cum = fmaf(ew[j], rw, cum + 1e-4f);         // xpos[j+1]
  }
  float bw = fmaf(ewk, rw, 1e-4f);

  float eh[8]; float shs = 0.f;
#pragma unroll
  for (int k = 0; k < 8; ++k){ eh[k] = fexp(p[8 + k]); shs += eh[k]; }
  float rh = frcp(shs) * 19.9992f;

  float S = 0.f, ehk = eh[0];
#pragma unroll
  for (int k = 1; k < 8; ++k){
    bool sel = (idx >= k);
    S   += sel ? eh[k - 1] : 0.f;
    ehk  = sel ? eh[k]     : ehk;
  }
  float yk = fmaf(S, rh, fmaf((float)idx, 1e-4f, -10.f));
  float bh = fmaf(ehk, rh, 1e-4f);

  float uA = p[16], uB = p[17];
#pragma unroll
  for (int j = 1; j < 8; ++j){
    bool sel = (idx >= j);
    uA = sel ? p[16 + j] : uA;
    uB = sel ? p[17 + j] : uB;
  }
  float vA = uA + 0.54116666f;
  float dk  = fmaxf(vA, 0.f) + flog(1.f + fexp(-fabsf(vA))) + 1e-4f;
  float vB = uB + 0.54116666f;
  float dk1 = fmaxf(vB, 0.f) + flog(1.f + fexp(-fabsf(vB))) + 1e-4f;

  float rbw = frcp(bw);
  float s   = bh * rbw;
  float zf  = fminf(fmaxf((xv - xk) * rbw, 0.f), 1.f);
  float z1  = 1.f - zf;
  float zz  = zf * zf, z01 = zf * z1;
  float den = s + (dk1 + dk - 2.f * s) * z01;
  float rden = frcp(den);
  float yv  = yk + bh * (s * zz + dk * z01) * rden;
  float num = dk1 * zz + 2.f * s * z01 + dk * z1 * z1;
  float ldv = flog(s * s * num * rden * rden);

  bool outside = (xv <= -10.f) || (xv >= 10.f);
  y_out  = outside ? xv : yv;
  ld_out = outside ? 0.f : ldv;
}

// ---------------- prep kernel: pack fp16 B-fragments into ws ----------------
extern "C" __global__ void __launch_bounds__(256)
prep_kernel(const float* __restrict__ W1, const float* __restrict__ W2,
            const float* __restrict__ Wo, const float* __restrict__ bout,
            const float* __restrict__ scale, char* __restrict__ ws)
{
  int tid = blockIdx.x * 256 + threadIdx.x;
  if (tid < 1024){                       // W1 frags: [L][nt2]
    int fi = tid >> 6, lane = tid & 63;
    int l = fi >> 1, nt = fi & 1;
    int n = nt * 32 + (lane & 31), khi = lane >> 5;
    half8 h;
#pragma unroll
    for (int j = 0; j < 8; ++j){ int k = khi * 8 + j; h[j] = (f16)W1[l * 1024 + k * 64 + n]; }
    *(half8*)(ws + W1F_OFF + fi * 1024 + lane * 16) = h;
  } else if (tid < 5120){                // W2 frags: [L][kt4][nt2]
    int idx = tid - 1024;
    int fi = idx >> 6, lane = idx & 63;
    int l = fi >> 3, kt = (fi >> 1) & 3, nt = fi & 1;
    int n = nt * 32 + (lane & 31), khi = lane >> 5;
    half8 h;
#pragma unroll
    for (int j = 0; j < 8; ++j){ int k = kt * 16 + khi * 8 + j; h[j] = (f16)W2[l * 4096 + k * 64 + n]; }
    *(half8*)(ws + W2F_OFF + fi * 1024 + lane * 16) = h;
  } else if (tid < 21504){               // Wout used-col frags: [L][u8][kt4]
    int idx = tid - 5120;
    int fi = idx >> 6, lane = idx & 63;
    int l = fi >> 5, u = (fi >> 2) & 7, kt = fi & 3;
    int f = (l & 1) + 2 * u;
    int c = lane & 31, khi = lane >> 5;
    half8 h;
#pragma unroll
    for (int j = 0; j < 8; ++j){
      int k = kt * 16 + khi * 8 + j;
      float v = (c < 25) ? Wo[l * 25600 + k * 400 + f * 25 + c] : 0.f;
      h[j] = (f16)v;
    }
    *(half8*)(ws + WOF_OFF + fi * 1024 + lane * 16) = h;
  } else if (tid < 23552){               // bout used cols: [L][u8][32] fp32
    int idx = tid - 21504;
    int l = idx >> 8, u = (idx >> 5) & 7, c = idx & 31;
    int f = (l & 1) + 2 * u;
    float v = (c < 25) ? bout[l * 400 + f * 25 + c] : 0.f;
    ((float*)(ws + BOF_OFF))[idx] = v;
  } else if (tid == 23552){              // sum of log|scale| over all layers
    float acc = 0.f;
    for (int i = 0; i < 128; ++i) acc += logf(fabsf(scale[i]));
    *(float*)(ws + SUMLOG_OFF) = acc;
  }
}

// ---------------- one coupling layer ----------------
// Wave owns 32 samples; lane pair (ln31, khi=0/1) shares sample ln31.
// khi=0 splines features PAR+2it (it=0..3), khi=1 splines PAR+2it+8 —
// same instruction stream, no divergence. z exchanged via shfl_xor(32).
template<int PAR>
DEV void layer_mfma(int l,
                    const float* __restrict__ W0, const float* __restrict__ b0,
                    const float* __restrict__ b1v, const float* __restrict__ b2v,
                    const float* __restrict__ scv, const float* __restrict__ shv,
                    const char* __restrict__ ws, char* wlds /*per-wave chunk*/,
                    float (&z)[16], float &logdet,
                    int lane, int ln31, int khi)
{
  const float* w0  = W0 + l * 256;
  const float* bb0 = b0 + l * 16;
  const int rowbase = khi * 4;     // C/D layout: row = (i&3)+8*(i>>2)+4*khi

  const half8* W1F = (const half8*)(ws + W1F_OFF);
  const half8* W2F = (const half8*)(ws + W2F_OFF);
  const half8* WOF = (const half8*)(ws + WOF_OFF);
  const float* BOF = (const float*)(ws + BOF_OFF);

  // ---- hoisted W1 fragment + bias loads (latency hidden behind h0) ----
  half8 w1f[2];
#pragma unroll
  for (int nt = 0; nt < 2; ++nt) w1f[nt] = W1F[(l * 2 + nt) * 64 + lane];
  float bias1[2], bias2[2];
#pragma unroll
  for (int nt = 0; nt < 2; ++nt){
    bias1[nt] = b1v[l * 64 + nt * 32 + ln31];
    bias2[nt] = b2v[l * 64 + nt * 32 + ln31];
  }

  // ---- h0 = tanh(mz @ W0 + b0): scalar weights; keep own khi-half as
  //      the W1 A-fragment. No LDS round-trip. ----
  float h0[16];
#pragma unroll
  for (int j = 0; j < 16; ++j) h0[j] = bb0[j];
#pragma unroll
  for (int u = 0; u < 8; ++u){
    const int f = (1 - PAR) + 2 * u;
    const float v = z[f];
#pragma unroll
    for (int j = 0; j < 16; ++j) h0[j] = fmaf(v, w0[f * 16 + j], h0[j]);
  }
  half8 a0;
#pragma unroll
  for (int j = 0; j < 8; ++j){
    float hv = khi ? h0[j + 8] : h0[j];
    a0[j] = (f16)ftanh(hv);
  }

  // ---- W1: h1 = tanh(h0 @ W1 + b1), 1 m-tile ----
  f32x16 d1[2];
#pragma unroll
  for (int nt = 0; nt < 2; ++nt)
#pragma unroll
    for (int i = 0; i < 16; ++i) d1[nt][i] = bias1[nt];
#pragma unroll
  for (int nt = 0; nt < 2; ++nt)
    d1[nt] = __builtin_amdgcn_mfma_f32_32x32x16_f16(a0, w1f[nt], d1[nt], 0, 0, 0);

  // load W2 frags now; the d1 epilogue below covers the latency
  half8 w2f[8];
#pragma unroll
  for (int kt = 0; kt < 4; ++kt)
#pragma unroll
    for (int nt = 0; nt < 2; ++nt)
      w2f[kt * 2 + nt] = W2F[((l * 4 + kt) * 2 + nt) * 64 + lane];

#pragma unroll
  for (int nt = 0; nt < 2; ++nt)
#pragma unroll
    for (int i = 0; i < 16; ++i){
      int row = (i & 3) + 8 * (i >> 2) + rowbase;
      *(f16*)(wlds + row * H_STRIDE + (nt * 32 + ln31) * 2) = (f16)ftanh(d1[nt][i]);
    }

  // ---- W2: h2 = h1 @ W2 + b2 ----
  half8 a1[4];
#pragma unroll
  for (int kt = 0; kt < 4; ++kt)
    a1[kt] = *(const half8*)(wlds + ln31 * H_STRIDE + kt * 32 + khi * 16);
  f32x16 d2[2];
#pragma unroll
  for (int nt = 0; nt < 2; ++nt)
#pragma unroll
    for (int i = 0; i < 16; ++i) d2[nt][i] = bias2[nt];
#pragma unroll
  for (int kt = 0; kt < 4; ++kt)
#pragma unroll
    for (int nt = 0; nt < 2; ++nt)
      d2[nt] = __builtin_amdgcn_mfma_f32_32x32x16_f16(a1[kt], w2f[kt * 2 + nt], d2[nt], 0, 0, 0);

  // prefetch production 0's A-side Wout frags during the d2 epilogue
  half8 bfA[4];
#pragma unroll
  for (int kt = 0; kt < 4; ++kt) bfA[kt] = WOF[((l * 8 + 0) * 4 + kt) * 64 + lane];
  float biasA = BOF[(l * 8 + 0) * 32 + ln31];

#pragma unroll
  for (int nt = 0; nt < 2; ++nt)
#pragma unroll
    for (int i = 0; i < 16; ++i){
      int row = (i & 3) + 8 * (i >> 2) + rowbase;
      *(f16*)(wlds + row * H_STRIDE + (nt * 32 + ln31) * 2) = (f16)d2[nt][i];
    }

  // ---- h2 A-fragments (live across all 4 production iterations) ----
  half8 a2[4];
#pragma unroll
  for (int kt = 0; kt < 4; ++kt)
    a2[kt] = *(const half8*)(wlds + ln31 * H_STRIDE + kt * 32 + khi * 16);

  // ---- paired productions + splines (sequential dp to cap registers) ----
#pragma unroll 1
  for (int it = 0; it < 4; ++it){
    // B-side frags: issue loads, then cover latency with dpA's MFMA+store
    half8 bfB[4];
#pragma unroll
    for (int kt = 0; kt < 4; ++kt) bfB[kt] = WOF[((l * 8 + it + 4) * 4 + kt) * 64 + lane];
    float biasB = BOF[(l * 8 + it + 4) * 32 + ln31];

    {
      f32x16 dp;
#pragma unroll
      for (int i = 0; i < 16; ++i) dp[i] = biasA;
#pragma unroll
      for (int kt = 0; kt < 4; ++kt)
        dp = __builtin_amdgcn_mfma_f32_32x32x16_f16(a2[kt], bfA[kt], dp, 0, 0, 0);
      if (ln31 < 25){
#pragma unroll
        for (int i = 0; i < 16; ++i){
          int row = (i & 3) + 8 * (i >> 2) + rowbase;
          *(float*)(wlds + row * P_STRIDE + ln31 * 4) = dp[i];
        }
      }
    }
    {
      f32x16 dp;
#pragma unroll
      for (int i = 0; i < 16; ++i) dp[i] = biasB;
#pragma unroll
      for (int kt = 0; kt < 4; ++kt)
        dp = __builtin_amdgcn_mfma_f32_32x32x16_f16(a2[kt], bfB[kt], dp, 0, 0, 0);
      if (ln31 < 25){
#pragma unroll
        for (int i = 0; i < 16; ++i){
          int row = (i & 3) + 8 * (i >> 2) + rowbase;
          *(float*)(wlds + P_SLOT + row * P_STRIDE + ln31 * 4) = dp[i];
        }
      }
    }

    // prefetch next iteration's A-side frags; spline below hides the latency
    if (it < 3){
#pragma unroll
      for (int kt = 0; kt < 4; ++kt) bfA[kt] = WOF[((l * 8 + it + 1) * 4 + kt) * 64 + lane];
      biasA = BOF[(l * 8 + it + 1) * 32 + ln31];
    }

    // own-sample read from own khi-slot (in-order per-wave DS => safe)
    const char* pb = wlds + khi * P_SLOT + ln31 * P_STRIDE;
    float p[25];
#pragma unroll
    for (int j = 0; j < 25; ++j) p[j] = *(const float*)(pb + j * 4);

    float xlo = z[PAR + 2 * it], xhi = z[PAR + 2 * it + 8];
    float xin = khi ? xhi : xlo;
    float y, ld;
    rq_spline(p, xin, y, ld);
    logdet += ld;
    z[PAR + 2 * it]     = khi ? xlo : y;
    z[PAR + 2 * it + 8] = khi ? y : xhi;
  }

  // ---- exchange transformed features between the khi-halves ----
#pragma unroll
  for (int it = 0; it < 4; ++it){
    float mine  = khi ? z[PAR + 2 * it + 8] : z[PAR + 2 * it];
    float other = __shfl_xor(mine, 32, 64);
    z[PAR + 2 * it]     = khi ? other : z[PAR + 2 * it];
    z[PAR + 2 * it + 8] = khi ? z[PAR + 2 * it + 8] : other;
  }

  // ---- affine (log|scale| sum precomputed in prep) ----
  const float* scp = scv + l * 16;
  const float* shp = shv + l * 16;
#pragma unroll
  for (int j = 0; j < 16; ++j)
    z[j] = fmaf(z[j], scp[j], shp[j]);
}

extern "C" __global__ void __launch_bounds__(256, 4)
flow_kernel(const float* __restrict__ x,
            const float* __restrict__ W0, const float* __restrict__ b0,
            const float* __restrict__ b1v, const float* __restrict__ b2v,
            const float* __restrict__ scv, const float* __restrict__ shv,
            const char* __restrict__ ws, float* __restrict__ out, int B)
{
  extern __shared__ char lds[];
  const int t    = threadIdx.x;
  const int lane = t & 63;
  const int wv   = t >> 6;
  const int ln31 = lane & 31;
  const int khi  = lane >> 5;
  char* wlds = lds + wv * WCHUNK;          // per-wave private chunk

  const int sid = wv * 32 + ln31;          // sample within block (0..127)
  const int g   = blockIdx.x * 128 + sid;  // global sample

  float z[16];
  const float4* xv = reinterpret_cast<const float4*>(x + (size_t)g * 16);
  float4 a0 = xv[0], a1 = xv[1], a2 = xv[2], a3 = xv[3];
  z[0]=a0.x; z[1]=a0.y; z[2]=a0.z; z[3]=a0.w;
  z[4]=a1.x; z[5]=a1.y; z[6]=a1.z; z[7]=a1.w;
  z[8]=a2.x; z[9]=a2.y; z[10]=a2.z; z[11]=a2.w;
  z[12]=a3.x; z[13]=a3.y; z[14]=a3.z; z[15]=a3.w;

  float logdet = 0.f;
  for (int l = 7; l >= 0; --l){
    if (l & 1) layer_mfma<1>(l, W0, b0, b1v, b2v, scv, shv, ws, wlds, z, logdet, lane, ln31, khi);
    else       layer_mfma<0>(l, W0, b0, b1v, b2v, scv, shv, ws, wlds, z, logdet, lane, ln31, khi);
  }

  // combine the pair's logdet halves
  float ldtot = logdet + __shfl_xor(logdet, 32, 64);

  float sumlog = *(const float*)(ws + SUMLOG_OFF);
  float ss = 0.f;
#pragma unroll
  for (int j = 0; j < 16; ++j) ss = fmaf(z[j], z[j], ss);
  if (khi == 0)
    out[g] = -0.5f * ss - 14.7030165f + ldtot + sumlog;
}

extern "C" void kernel_launch(void* const* d_in, const int* in_sizes, int n_in,
                              void* d_out, int out_size, void* d_ws, size_t ws_size,
                              hipStream_t stream)
{
  const float* x    = (const float*)d_in[0];
  const float* W0   = (const float*)d_in[1];
  const float* b0   = (const float*)d_in[2];
  const float* W1   = (const float*)d_in[3];
  const float* b1   = (const float*)d_in[4];
  const float* W2   = (const float*)d_in[5];
  const float* b2   = (const float*)d_in[6];
  const float* Wout = (const float*)d_in[7];
  const float* bout = (const float*)d_in[8];
  const float* scale= (const float*)d_in[9];
  const float* shift= (const float*)d_in[10];

  int B = in_sizes[0] / 16;

  hipLaunchKernelGGL(prep_kernel, dim3(93), dim3(256), 0, stream,
                     W1, W2, Wout, bout, scale, (char*)d_ws);

  hipLaunchKernelGGL(flow_kernel, dim3(B / 128), dim3(256), LDS_BYTES, stream,
                     x, W0, b0, b1, b2, scale, shift,
                     (const char*)d_ws, (float*)d_out, B);
}